// Round 6
// baseline (210.094 us; speedup 1.0000x reference)
//
#include <hip/hip_runtime.h>
#include <cstddef>
#include <cstdint>

// Problem constants (fixed by the reference setup)
static constexpr int kNodes   = 20000;
static constexpr int kEdges   = 640000;
static constexpr int kCin     = 128;
static constexpr int kFolds   = 8;
static constexpr int kFilters = 128;
static constexpr int kKdim    = 1024;

// Binned edge reorg
static constexpr int kRowsPerBin = 16;
static constexpr int kBins  = kNodes / kRowsPerBin;  // 1250
static constexpr int kSubs  = 8;                     // sub-buckets per bin
static constexpr int kCapX  = 128;                   // per (bin,sub); mean 64, +8 sigma
static constexpr int kRecDW = 5;                     // meta + 4 dwords (8x bf16 ef)
static constexpr int kMaxRec = kSubs * kCapX;        // 1024 records per bin

// LDS S-tile stride: 1024 + 8 shorts -> 516 dwords == 4 (mod 32): b128 reads
// across 16 rows hit banks {4m mod 32} -> 2-way aliasing (free, m136).
static constexpr int kSStride = 1032;

typedef __attribute__((ext_vector_type(8))) short v8s;
typedef __attribute__((ext_vector_type(4))) float v4f;
typedef __attribute__((ext_vector_type(2))) float v2f;

// round-to-nearest-even fp32 -> bf16
__device__ __forceinline__ unsigned short f2bf(float f) {
    union { float f; uint32_t u; } v; v.f = f;
    const uint32_t u = v.u;
    return (unsigned short)((u + 0x7fffu + ((u >> 16) & 1u)) >> 16);
}
__device__ __forceinline__ float bfLo(uint32_t d) {   // low 16 bits as bf16
    union { uint32_t u; float f; } v; v.u = d << 16;
    return v.f;
}
__device__ __forceinline__ float bfHi(uint32_t d) {   // high 16 bits as bf16
    union { uint32_t u; float f; } v; v.u = d & 0xFFFF0000u;
    return v.f;
}

// ---------------------------------------------------------------------------
// Fused prep. blockIdx ranges:
//   [0,2500):    edge work — bin by row>>4, sub-bucket = blockIdx&7,
//                record = {col | (row&15)<<16, 8x bf16 ef} (5 dwords)
//   [2500,3750): x fp32 -> bf16
//   [3750,3814): W (1024,128) fp32 -> Wt (128,1024) bf16 transposed
// ---------------------------------------------------------------------------
__global__ __launch_bounds__(256) void prep_k(
    const int2*  __restrict__ idx2,   // (kEdges): {row, col}
    const float* __restrict__ ef,     // (8, kEdges)
    const float* __restrict__ x,      // (kNodes, 128)
    const float* __restrict__ W,      // (1024, 128)
    int*      __restrict__ cnt,       // (kBins*kSubs), zeroed
    uint32_t* __restrict__ binbuf,    // (kBins*kSubs, kCapX, 5) dwords
    unsigned short* __restrict__ xb,  // (kNodes, 128) bf16
    unsigned short* __restrict__ Wt)  // (128, 1024) bf16
{
    const int b = blockIdx.x;
    const int t = threadIdx.x;
    if (b < 2500) {
        const int e = b * 256 + t;
        const int2 rc = idx2[e];                  // {row, col}
        uint32_t efd[4];
        #pragma unroll
        for (int k = 0; k < 4; ++k) {
            const unsigned short lo = f2bf(ef[(size_t)(2 * k) * kEdges + e]);
            const unsigned short hi = f2bf(ef[(size_t)(2 * k + 1) * kEdges + e]);
            efd[k] = (uint32_t)lo | ((uint32_t)hi << 16);
        }
        const int bin  = rc.x >> 4;
        const int slot = bin * kSubs + (b & 7);
        const int p = atomicAdd(&cnt[slot], 1);
        if (p < kCapX) {
            uint32_t* dst = binbuf + ((size_t)slot * kCapX + p) * kRecDW;
            dst[0] = (uint32_t)rc.y | ((uint32_t)(rc.x & 15) << 16);
            dst[1] = efd[0]; dst[2] = efd[1]; dst[3] = efd[2]; dst[4] = efd[3];
        }
    } else if (b < 3750) {
        const int i = (b - 2500) * 2048 + t * 8;
        const float4 a = *(const float4*)(x + i);
        const float4 c = *(const float4*)(x + i + 4);
        union { uint4 q; unsigned short s[8]; } o;
        o.s[0] = f2bf(a.x); o.s[1] = f2bf(a.y); o.s[2] = f2bf(a.z); o.s[3] = f2bf(a.w);
        o.s[4] = f2bf(c.x); o.s[5] = f2bf(c.y); o.s[6] = f2bf(c.z); o.s[7] = f2bf(c.w);
        *(uint4*)(xb + i) = o.q;
    } else {
        const int t2 = (b - 3750) * 256 + t;      // 16384 threads
        const int n  = t2 & 127;
        const int k8 = t2 >> 7;
        union { uint4 q; unsigned short s[8]; } o;
        #pragma unroll
        for (int j = 0; j < 8; ++j)
            o.s[j] = f2bf(W[(size_t)(k8 * 8 + j) * kFilters + n]);
        *(uint4*)(Wt + (size_t)n * kKdim + k8 * 8) = o.q;
    }
}

// ---------------------------------------------------------------------------
// Fused pull+GEMM: one block (256 thr) per bin of 16 rows.
// Phase A: coalesced-load bin records to LDS, counting-sort by row, then
//   thread (row, 8 ch) accumulates all 8 folds in registers (x row loaded &
//   converted once per edge, depth-2 pipelined gather, packed-f32 FMA).
// Phase B: S-tile (16x1024 bf16) written to LDS (overlaying dead record buf),
//   then 16x1024 @ 1024x128 MFMA GEMM with B-frags streamed straight from
//   the L2-hot Wt (no staging, no barriers), bias fused, out written direct.
// ---------------------------------------------------------------------------
__global__ __launch_bounds__(256, 4) void fused_k(
    const unsigned short* __restrict__ xb,     // (kNodes,128) bf16
    const int*      __restrict__ cnt,          // (kBins*kSubs)
    const uint32_t* __restrict__ binbuf,
    const unsigned short* __restrict__ Wt,     // (128,1024) bf16 transposed
    const float* __restrict__ bias,            // (128)
    float* __restrict__ out)                   // (kNodes,128)
{
    __shared__ __align__(16) char smem[kRowsPerBin * kSStride * 2];  // 33 KB
    __shared__ int sCnt[kSubs];
    __shared__ int sOfs[kSubs + 1];
    __shared__ int sRs[kRowsPerBin + 1];
    __shared__ int sRofs[kRowsPerBin];
    __shared__ int sRcnt[kRowsPerBin];

    uint32_t*       sRec  = (uint32_t*)smem;                    // 20480 B
    unsigned short* sPerm = (unsigned short*)(smem + 20480);    //  2048 B
    unsigned short* sS    = (unsigned short*)smem;              // phase B overlay

    const int bin = blockIdx.x;
    const int t   = threadIdx.x;

    if (t < kSubs) {
        int c = cnt[bin * kSubs + t];
        sCnt[t] = c < kCapX ? c : kCapX;
    }
    if (t < kRowsPerBin) sRcnt[t] = 0;
    __syncthreads();
    if (t == 0) {
        int a = 0;
        #pragma unroll
        for (int s = 0; s < kSubs; ++s) { sOfs[s] = a; a += sCnt[s]; }
        sOfs[kSubs] = a;
    }
    __syncthreads();

    // coalesced copy of all sub-segments into dense LDS
    #pragma unroll
    for (int s = 0; s < kSubs; ++s) {
        const int nd = sCnt[s] * kRecDW;
        const uint32_t* g = binbuf + (size_t)(bin * kSubs + s) * kCapX * kRecDW;
        uint32_t* d = sRec + sOfs[s] * kRecDW;
        for (int i = t; i < nd; i += 256) d[i] = g[i];
    }
    const int T = sOfs[kSubs];
    __syncthreads();

    // counting sort by row-within-bin
    for (int j = t; j < T; j += 256)
        atomicAdd(&sRcnt[(sRec[j * kRecDW] >> 16) & 15], 1);
    __syncthreads();
    if (t == 0) {
        int a = 0;
        #pragma unroll
        for (int r = 0; r < kRowsPerBin; ++r) { sRs[r] = a; sRofs[r] = a; a += sRcnt[r]; }
        sRs[kRowsPerBin] = a;
    }
    __syncthreads();
    for (int j = t; j < T; j += 256) {
        const int r = (sRec[j * kRecDW] >> 16) & 15;
        const int pos = atomicAdd(&sRofs[r], 1);
        sPerm[pos] = (unsigned short)j;
    }
    __syncthreads();

    // ---- Phase A accumulate: thread = (row r, channels c8..c8+7), 8 folds ---
    const int r    = t >> 4;
    const int c8   = (t & 15) * 8;
    const int base = sRs[r];
    const int deg  = sRs[r + 1] - base;

    v2f acc[8][4];
    #pragma unroll
    for (int k = 0; k < 8; ++k)
        #pragma unroll
        for (int j = 0; j < 4; ++j) acc[k][j] = (v2f){0.f, 0.f};

    const unsigned short* xbase = xb + c8;
    int j0 = 0, j1 = 0;
    v8s x0, x1;
    if (deg > 0) {
        j0 = sPerm[base];
        x0 = *(const v8s*)(xbase + (size_t)(sRec[j0 * kRecDW] & 0xFFFF) * kCin);
    }
    if (deg > 1) {
        j1 = sPerm[base + 1];
        x1 = *(const v8s*)(xbase + (size_t)(sRec[j1 * kRecDW] & 0xFFFF) * kCin);
    }

    for (int i = 0; i < deg; ++i) {
        int jn = j1;
        v8s xn = x1;
        if (i + 2 < deg) {                       // depth-2 pipelined gather
            jn = sPerm[base + i + 2];
            xn = *(const v8s*)(xbase + (size_t)(sRec[jn * kRecDW] & 0xFFFF) * kCin);
        }
        const uint32_t* rec = &sRec[j0 * kRecDW];
        float w[8];
        #pragma unroll
        for (int k = 0; k < 4; ++k) {
            const uint32_t d = rec[1 + k];       // broadcast across 16 lanes
            w[2 * k]     = bfLo(d);
            w[2 * k + 1] = bfHi(d);
        }
        const uint32_t* xd = (const uint32_t*)&x0;
        v2f xf[4];
        #pragma unroll
        for (int j = 0; j < 4; ++j)
            xf[j] = (v2f){bfLo(xd[j]), bfHi(xd[j])};
        #pragma unroll
        for (int k = 0; k < 8; ++k) {
            const v2f wv = (v2f){w[k], w[k]};
            #pragma unroll
            for (int j = 0; j < 4; ++j)
                acc[k][j] += wv * xf[j];         // v_pk_fma_f32
        }
        j0 = j1; x0 = x1;
        j1 = jn; x1 = xn;
    }
    __syncthreads();   // all sRec/sPerm reads done before sS overlay

    // ---- write S-tile (bf16) into LDS ----
    #pragma unroll
    for (int k = 0; k < 8; ++k) {
        union { uint4 q; unsigned short s[8]; } o;
        #pragma unroll
        for (int j = 0; j < 4; ++j) {
            o.s[2 * j]     = f2bf(acc[k][j][0]);
            o.s[2 * j + 1] = f2bf(acc[k][j][1]);
        }
        *(uint4*)&sS[r * kSStride + k * kCin + c8] = o.q;
    }
    __syncthreads();

    // ---- Phase B: 16x1024 @ 1024x128 MFMA, B-frags straight from L2 ----
    const int lane = t & 63;
    const int wave = t >> 6;
    const int quad = lane >> 4;
    const int n16  = lane & 15;

    const unsigned short* wt0 = Wt + (size_t)(wave * 32 + n16) * kKdim + quad * 8;
    const unsigned short* wt1 = wt0 + (size_t)16 * kKdim;

    v4f o0 = (v4f){0.f, 0.f, 0.f, 0.f};
    v4f o1 = (v4f){0.f, 0.f, 0.f, 0.f};
    #pragma unroll 4
    for (int k0 = 0; k0 < 32; ++k0) {
        const v8s a  = *(const v8s*)&sS[n16 * kSStride + k0 * 32 + quad * 8];
        const v8s b0 = *(const v8s*)(wt0 + k0 * 32);
        const v8s b1 = *(const v8s*)(wt1 + k0 * 32);
        o0 = __builtin_amdgcn_mfma_f32_16x16x32_bf16(a, b0, o0, 0, 0, 0);
        o1 = __builtin_amdgcn_mfma_f32_16x16x32_bf16(a, b1, o1, 0, 0, 0);
    }

    // epilogue: C/D col=lane&15, row=quad*4+reg
    const int nA = wave * 32 + n16;
    const int nB = nA + 16;
    const float bA = bias[nA];
    const float bB = bias[nB];
    #pragma unroll
    for (int rr = 0; rr < 4; ++rr) {
        const int m = bin * kRowsPerBin + quad * 4 + rr;
        out[(size_t)m * kFilters + nA] = o0[rr] + bA;
        out[(size_t)m * kFilters + nB] = o1[rr] + bB;
    }
}

extern "C" void kernel_launch(void* const* d_in, const int* in_sizes, int n_in,
                              void* d_out, int out_size, void* d_ws, size_t ws_size,
                              hipStream_t stream) {
    const float* x    = (const float*)d_in[0];   // (20000,128)
    const float* ef   = (const float*)d_in[1];   // (8,640000)
    const float* W    = (const float*)d_in[2];   // (8,128,128)
    const float* bias = (const float*)d_in[3];   // (128)
    const int2*  idx2 = (const int2*)d_in[4];    // (640000,2) int32
    float* out = (float*)d_out;                  // (20000,128)

    // ws layout (16B-aligned), total ~31.1 MB
    char* ws = (char*)d_ws;
    uint32_t*       binbuf = (uint32_t*)(ws);                    // 25,600,000
    unsigned short* xb     = (unsigned short*)(ws + 25600000);   //  5,120,000
    unsigned short* Wt     = (unsigned short*)(ws + 30720000);   //    262,144
    int*            cnt    = (int*)(ws + 30982144);              //     40,000

    hipMemsetAsync(cnt, 0, kBins * kSubs * sizeof(int), stream);

    prep_k<<<3814, 256, 0, stream>>>(idx2, ef, x, W, cnt, binbuf, xb, Wt);
    fused_k<<<kBins, 256, 0, stream>>>(xb, cnt, binbuf, Wt, bias, out);
}

// Round 7
// 203.981 us; speedup vs baseline: 1.0300x; 1.0300x over previous
//
#include <hip/hip_runtime.h>
#include <cstddef>
#include <cstdint>

// Problem constants (fixed by the reference setup)
static constexpr int kNodes   = 20000;
static constexpr int kEdges   = 640000;
static constexpr int kCin     = 128;
static constexpr int kFolds   = 8;
static constexpr int kFilters = 128;
static constexpr int kKdim    = 1024;
static constexpr int kCap     = 80;   // per-node bucket; Poisson(32) tail >80 ~1.5e-13

typedef __attribute__((ext_vector_type(8))) short v8s;
typedef __attribute__((ext_vector_type(4))) float v4f;
typedef __attribute__((ext_vector_type(2))) float v2f;

// round-to-nearest-even fp32 -> bf16
__device__ __forceinline__ unsigned short f2bf(float f) {
    union { float f; uint32_t u; } v; v.f = f;
    const uint32_t u = v.u;
    return (unsigned short)((u + 0x7fffu + ((u >> 16) & 1u)) >> 16);
}
__device__ __forceinline__ float bfLo(uint32_t d) {
    union { uint32_t u; float f; } v; v.u = d << 16;
    return v.f;
}
__device__ __forceinline__ float bfHi(uint32_t d) {
    union { uint32_t u; float f; } v; v.u = d & 0xFFFF0000u;
    return v.f;
}

// ---------------------------------------------------------------------------
// Fused prep. blockIdx ranges:
//   [0,2500):    edge scatter into per-node SoA buckets:
//                colbuf[node][p] = col (dword), efbuf[node][p] = 8x bf16 (uint4)
//   [2500,3750): x fp32 -> bf16
//   [3750,3814): W (1024,128) fp32 -> Wt (128,1024) bf16 transposed
// ---------------------------------------------------------------------------
__global__ __launch_bounds__(256) void prep_k(
    const int2*  __restrict__ idx2,   // (kEdges): {row, col}
    const float* __restrict__ ef,     // (8, kEdges)
    const float* __restrict__ x,      // (kNodes, 128)
    const float* __restrict__ W,      // (1024, 128)
    int*   __restrict__ cnt,          // (kNodes), zeroed
    int*   __restrict__ colbuf,       // (kNodes, kCap)
    uint4* __restrict__ efbuf,        // (kNodes, kCap)
    unsigned short* __restrict__ xb,  // (kNodes, 128) bf16
    unsigned short* __restrict__ Wt)  // (128, 1024) bf16
{
    const int b = blockIdx.x;
    const int t = threadIdx.x;
    if (b < 2500) {
        const int e = b * 256 + t;
        const int2 rc = idx2[e];                  // {row, col}
        uint32_t d[4];
        #pragma unroll
        for (int k = 0; k < 4; ++k) {
            const unsigned short lo = f2bf(ef[(size_t)(2 * k) * kEdges + e]);
            const unsigned short hi = f2bf(ef[(size_t)(2 * k + 1) * kEdges + e]);
            d[k] = (uint32_t)lo | ((uint32_t)hi << 16);
        }
        const int p = atomicAdd(&cnt[rc.x], 1);
        if (p < kCap) {
            colbuf[rc.x * kCap + p] = rc.y;
            efbuf[rc.x * kCap + p] = make_uint4(d[0], d[1], d[2], d[3]);
        }
    } else if (b < 3750) {
        const int i = (b - 2500) * 2048 + t * 8;
        const float4 a = *(const float4*)(x + i);
        const float4 c = *(const float4*)(x + i + 4);
        union { uint4 q; unsigned short s[8]; } o;
        o.s[0] = f2bf(a.x); o.s[1] = f2bf(a.y); o.s[2] = f2bf(a.z); o.s[3] = f2bf(a.w);
        o.s[4] = f2bf(c.x); o.s[5] = f2bf(c.y); o.s[6] = f2bf(c.z); o.s[7] = f2bf(c.w);
        *(uint4*)(xb + i) = o.q;
    } else {
        const int t2 = (b - 3750) * 256 + t;      // 16384 threads
        const int n  = t2 & 127;
        const int k8 = t2 >> 7;
        union { uint4 q; unsigned short s[8]; } o;
        #pragma unroll
        for (int j = 0; j < 8; ++j)
            o.s[j] = f2bf(W[(size_t)(k8 * 8 + j) * kFilters + n]);
        *(uint4*)(Wt + (size_t)n * kKdim + k8 * 8) = o.q;
    }
}

// ---------------------------------------------------------------------------
// Pull, one WAVE per node (4 waves / 256-thr block, zero barriers).
// Lane owns 2 channels (c2 = lane*2) for all 8 folds: acc[8] x float2.
// Per edge: ONE fully-coalesced wave-wide x-row load (64 lanes x 4 B = 256 B),
// ef via LDS 16 B broadcast, 8 packed-f32 FMA. Depth-2 pipelined gather.
// S row (1024 bf16) written with 8 coalesced 256 B dword stores.
// ---------------------------------------------------------------------------
__global__ __launch_bounds__(256) void pull_k(
    const unsigned short* __restrict__ xb,   // (kNodes,128) bf16
    const int*   __restrict__ cnt,           // (kNodes)
    const int*   __restrict__ colbuf,        // (kNodes,kCap)
    const uint4* __restrict__ efbuf,         // (kNodes,kCap)
    unsigned short* __restrict__ S)          // (kNodes,1024) bf16
{
    __shared__ int   sCol[4][kCap];          // 1280 B
    __shared__ uint4 sEf[4][kCap];           // 5120 B

    const int w    = threadIdx.x >> 6;       // wave in block
    const int lane = threadIdx.x & 63;
    const int n    = blockIdx.x * 4 + w;     // node (grid sized exactly: 5000*4)

    int deg = cnt[n];
    if (deg > kCap) deg = kCap;

    // per-wave staging (no barrier: producer wave == consumer wave)
    for (int i = lane; i < deg; i += 64) {
        sCol[w][i] = colbuf[n * kCap + i];
        sEf[w][i]  = efbuf[n * kCap + i];
    }

    v2f acc[8];
    #pragma unroll
    for (int k = 0; k < 8; ++k) acc[k] = (v2f){0.f, 0.f};

    const unsigned short* xbase = xb + lane * 2;   // lane's 2-channel slot
    uint32_t xd0 = 0, xd1 = 0;
    if (deg > 0) xd0 = *(const uint32_t*)(xbase + (size_t)sCol[w][0] * kCin);
    if (deg > 1) xd1 = *(const uint32_t*)(xbase + (size_t)sCol[w][1] * kCin);

    for (int i = 0; i < deg; ++i) {
        uint32_t xdn = xd1;
        if (i + 2 < deg)                           // depth-2 pipelined gather
            xdn = *(const uint32_t*)(xbase + (size_t)sCol[w][i + 2] * kCin);

        const uint4 e4 = sEf[w][i];                // broadcast (same addr all lanes)
        const v2f xf = (v2f){bfLo(xd0), bfHi(xd0)};

        float wk[8];
        wk[0] = bfLo(e4.x); wk[1] = bfHi(e4.x);
        wk[2] = bfLo(e4.y); wk[3] = bfHi(e4.y);
        wk[4] = bfLo(e4.z); wk[5] = bfHi(e4.z);
        wk[6] = bfLo(e4.w); wk[7] = bfHi(e4.w);

        #pragma unroll
        for (int k = 0; k < 8; ++k)
            acc[k] += (v2f){wk[k], wk[k]} * xf;    // v_pk_fma_f32

        xd0 = xd1; xd1 = xdn;
    }

    // write S row: fold k at S[n*1024 + k*128 + lane*2], 256 B coalesced each
    unsigned short* srow = S + (size_t)n * kKdim + lane * 2;
    #pragma unroll
    for (int k = 0; k < 8; ++k) {
        const uint32_t o = (uint32_t)f2bf(acc[k][0]) | ((uint32_t)f2bf(acc[k][1]) << 16);
        *(uint32_t*)(srow + k * kCin) = o;
    }
}

// ---------------------------------------------------------------------------
// GEMM: out(20000x128) = S(20000x1024)bf16 @ W(1024x128)bf16 + bias.
// BM=16 -> 1250 blocks (4.9/CU). 256 thr / 4 waves; wave w covers 32 cols
// (2 n-tiles), all 16 rows. BK=32 staged in LDS (stride 40 shorts).
// Fragment layouts (verified): A[m=lane&15][k=quad*8+j];
// B[k=quad*8+j][n=lane&15]; C/D col=lane&15, row=quad*4+reg.
// ---------------------------------------------------------------------------
static constexpr int BM  = 16;
static constexpr int BK  = 32;
static constexpr int SWS = 40;   // padded LDS stride in shorts (80 B)

__global__ __launch_bounds__(256) void gemm_k(
    const unsigned short* __restrict__ S,    // (kNodes,1024) bf16
    const unsigned short* __restrict__ Wt,   // (128,1024) bf16 transposed
    const float* __restrict__ bias,          // (128)
    float* __restrict__ out)                 // (kNodes,128)
{
    __shared__ unsigned short sS[BM * SWS];        // 1280 B
    __shared__ unsigned short sW[kFilters * SWS];  // 10240 B

    const int t    = threadIdx.x;
    const int wave = t >> 6;
    const int lane = t & 63;
    const int quad = lane >> 4;
    const int r16  = lane & 15;
    const int m0   = blockIdx.x * BM;              // 20000 % 16 == 0: no guards

    v4f acc0 = (v4f){0.f, 0.f, 0.f, 0.f};
    v4f acc1 = (v4f){0.f, 0.f, 0.f, 0.f};

    for (int k0 = 0; k0 < kKdim; k0 += BK) {
        // stage S tile: 16x32 = 512 elems, 1 dword (2 ch) per thread
        {
            const int row = t >> 4;
            const int kc  = (t & 15) * 2;
            *(uint32_t*)&sS[row * SWS + kc] =
                *(const uint32_t*)(S + (size_t)(m0 + row) * kKdim + k0 + kc);
        }
        // stage Wt tile: 128x32 = 4096 elems, 32 B per thread
        {
            const int n    = t >> 1;
            const int half = (t & 1) * 16;
            const unsigned short* src = Wt + (size_t)n * kKdim + k0 + half;
            *(uint4*)&sW[n * SWS + half]     = *(const uint4*)(src);
            *(uint4*)&sW[n * SWS + half + 8] = *(const uint4*)(src + 8);
        }
        __syncthreads();

        const v8s a  = *(const v8s*)&sS[r16 * SWS + quad * 8];
        const v8s b0 = *(const v8s*)&sW[(wave * 32 + r16) * SWS + quad * 8];
        const v8s b1 = *(const v8s*)&sW[(wave * 32 + 16 + r16) * SWS + quad * 8];
        acc0 = __builtin_amdgcn_mfma_f32_16x16x32_bf16(a, b0, acc0, 0, 0, 0);
        acc1 = __builtin_amdgcn_mfma_f32_16x16x32_bf16(a, b1, acc1, 0, 0, 0);
        __syncthreads();
    }

    // epilogue: C/D col=lane&15, row=quad*4+reg
    const int nA = wave * 32 + r16;
    const int nB = nA + 16;
    const float bA = bias[nA];
    const float bB = bias[nB];
    #pragma unroll
    for (int rr = 0; rr < 4; ++rr) {
        const int m = m0 + quad * 4 + rr;
        out[(size_t)m * kFilters + nA] = acc0[rr] + bA;
        out[(size_t)m * kFilters + nB] = acc1[rr] + bB;
    }
}

extern "C" void kernel_launch(void* const* d_in, const int* in_sizes, int n_in,
                              void* d_out, int out_size, void* d_ws, size_t ws_size,
                              hipStream_t stream) {
    const float* x    = (const float*)d_in[0];   // (20000,128)
    const float* ef   = (const float*)d_in[1];   // (8,640000)
    const float* W    = (const float*)d_in[2];   // (8,128,128)
    const float* bias = (const float*)d_in[3];   // (128)
    const int2*  idx2 = (const int2*)d_in[4];    // (640000,2) int32
    float* out = (float*)d_out;                  // (20000,128)

    // ws layout (16B-aligned), total ~78.4 MB (< proven >=81.9 MB)
    char* ws = (char*)d_ws;
    unsigned short* S      = (unsigned short*)(ws);              // 40,960,000
    uint4*          efbuf  = (uint4*)(ws + 40960000);            // 25,600,000
    int*            colbuf = (int*)(ws + 66560000);              //  6,400,000
    unsigned short* xb     = (unsigned short*)(ws + 72960000);   //  5,120,000
    unsigned short* Wt     = (unsigned short*)(ws + 78080000);   //    262,144
    int*            cnt    = (int*)(ws + 78342144);              //     80,000

    hipMemsetAsync(cnt, 0, kNodes * sizeof(int), stream);

    prep_k<<<3814, 256, 0, stream>>>(idx2, ef, x, W, cnt, colbuf, efbuf, xb, Wt);
    pull_k<<<kNodes / 4, 256, 0, stream>>>(xb, cnt, colbuf, efbuf, S);
    gemm_k<<<kNodes / BM, 256, 0, stream>>>(S, Wt, bias, out);
}